// Round 11
// baseline (4553.806 us; speedup 1.0000x reference)
//
#include <hip/hip_runtime.h>
#include <hip/hip_fp16.h>
#include <math.h>

// Problem dims (fixed by reference)
#define B 128
#define T 64
#define H 512
#define O 47
#define PP 4
#define G 2048         // 4*H
#define GH (G*H)
#define HB (H*B)       // 65536

// ===========================================================================
// PERSISTENT PATH A, round 11: h-part hoisted above the barrier + flat barrier.
// ---------------------------------------------------------------------------
// r10 result: plain-cached state loads (time-indexed slots) gave only -5% =>
// broadcast bytes no longer dominant. Phase = 12.1us with VALUBusy 36%:
// ~4.4us busy, ~7.7us idle = barrier latency + jitter + cold-miss latency
// right after the barrier (both GEMM inputs first-touched post-wait).
// This round restructures the dependency slack:
//  - h-part of phase p consumes state produced at barrier p-3 => compute the
//    ENTIRE h-half BEFORE waiting for barrier p-1. It overlaps straggler
//    epilogues + barrier propagation + its own cold misses.
//  - flat barrier: drop WG0-aggregation + go counter (2 serial IF hops);
//    every WG's 256 threads poll all 256 arrive flags directly.
//  - everything else = r10-A (proven): slot per (layer,t), plain 16B cached
//    state loads, agent stores, fp16 weights in LDS + fdot2, entry-only
//    acquire fence, launch_bounds(512,2) spill guard, folding (r1).
// Fallbacks: r9 kernel (path B) if ws small; legacy multi-launch last.
// ===========================================================================

typedef _Float16 h16;
typedef _Float16 h16x2 __attribute__((ext_vector_type(2)));

__device__ __forceinline__ unsigned int pack2h(float a, float b) {
    union { unsigned int u; h16 h[2]; } c;
    c.h[0] = (h16)a; c.h[1] = (h16)b;
    return c.u;
}
__device__ __forceinline__ h16x2 as_h2(unsigned int u) {
    union { unsigned int u; h16x2 v; } c; c.u = u; return c.v;
}
__device__ __forceinline__ uint2 cload_u2(const unsigned int* p) {
    unsigned long long v = __hip_atomic_load((const unsigned long long*)p,
                                             __ATOMIC_RELAXED, __HIP_MEMORY_SCOPE_AGENT);
    union { unsigned long long u; uint2 w; } c; c.u = v; return c.w;
}
__device__ __forceinline__ void cstore_u2(unsigned int* p, uint2 v) {
    union { unsigned long long u; uint2 w; } c; c.w = v;
    __hip_atomic_store((unsigned long long*)p, c.u,
                       __ATOMIC_RELAXED, __HIP_MEMORY_SCOPE_AGENT);
}
#define FDOT2(w, x, c) __builtin_amdgcn_fdot2(as_h2(w), as_h2(x), (c), false)

// LDS layout (float slots) — shared by both persistent kernels
#define SM_WH     0            // uint[6][8][256] packed half2 weights = 12288
#define SM_BIAS   12288        // [2][8][128] biasA/biasB planes       = 2048
#define SM_DECH   14336        // uint[256] dec row packed             = 256
#define SM_BL     14592        // [2][8] L1/L2 scalar biases           = 16
#define SM_G      14608        // gate partials (8192 floats)
#define SM_DB     22800        // dec partials  (1024 floats)
#define SM_H      23824        // [2][128] h staging                   = 256
#define SM_TOTAL  24080        // floats -> 96320 bytes

// path-A workspace offsets (float units)
#define HSLOT   32768                  // uints per state slot (256 kp x 128 b)
#define NSLOT   65                     // t = -1 .. 63
#define HTOT    (3 * NSLOT * HSLOT)    // 6,389,760
#define OFF_C   HTOT
#define OFF_M   (OFF_C + 3*HB)
#define OFF_W0  (OFF_M + 4*HB)
#define OFF_BA  (OFF_W0 + 16*HB)
#define OFF_BB  (OFF_BA + 4*HB)
#define OFF_DV  (OFF_BB + 4*HB)
#define OFF_BAR (OFF_DV + 5120)
#define NEED_A  ((size_t)(OFF_BAR + 4160) * sizeof(float))

struct RnnParams {
  const float* w_hh0;
  const float* w_ihr;
  const float* w_hhr;
  const float* b_ihr;
  const float* b_hhr;
  const float* dec_w;
  const float* dec_b;
  const float* W0eff;
  const float* biasA;
  const float* biasB;
  unsigned int* h;      // path A: 3*65 slots; path B: 6 ping-pong buffers
  float* c;
  float* out;
  unsigned int* arrive;
  unsigned int* gocnt;
};

// ---- precompute kernels (round 1, verified; layout-agnostic) ---------------

__global__ __launch_bounds__(256) void k_init_a(
    const float* __restrict__ enc_w, const float* __restrict__ enc_b,
    const float* __restrict__ dec_b,
    unsigned int* __restrict__ h, float* __restrict__ c,
    float* __restrict__ d, float* __restrict__ nxt0,
    unsigned int* __restrict__ barptr)
{
    int idx = blockIdx.x * 256 + threadIdx.x;   // 65536 threads
    if (idx < 4160) barptr[idx] = 0u;
    if (idx < HSLOT) {
        #pragma unroll
        for (int l = 0; l < 3; ++l) h[(size_t)l * NSLOT * HSLOT + idx] = 0u;
    }
    #pragma unroll
    for (int i = 0; i < 3; ++i) c[i*HB + idx] = 0.f;
    if (idx < H) {
        float s = 0.f;
        for (int o = 0; o < O; ++o) s += enc_w[idx*O + o] * dec_b[o];
        d[idx] = enc_b[idx] + s;
        nxt0[idx] = enc_w[idx*O + 1] + enc_b[idx];
    }
}

__global__ __launch_bounds__(256) void k_init_b(
    const float* __restrict__ enc_w, const float* __restrict__ enc_b,
    const float* __restrict__ dec_b,
    float* __restrict__ h, float* __restrict__ c,
    float* __restrict__ d, float* __restrict__ nxt0,
    unsigned int* __restrict__ barptr)
{
    int idx = blockIdx.x * 256 + threadIdx.x;
    if (idx < 4160) barptr[idx] = 0u;
    #pragma unroll
    for (int i = 0; i < 3; ++i) h[i*HB + idx] = 0.f;
    #pragma unroll
    for (int i = 0; i < 3; ++i) c[i*HB + idx] = 0.f;
    if (idx < H) {
        float s = 0.f;
        for (int o = 0; o < O; ++o) s += enc_w[idx*O + o] * dec_b[o];
        d[idx] = enc_b[idx] + s;
        nxt0[idx] = enc_w[idx*O + 1] + enc_b[idx];
    }
}

__global__ __launch_bounds__(256) void k_M(
    const float* __restrict__ enc_w, const float* __restrict__ dec_w,
    float* __restrict__ M)
{
    int idx = blockIdx.x * 256 + threadIdx.x;
    int hh = idx >> 9, k = idx & 511;
    float s = 0.f;
    for (int o = 0; o < O; ++o) s += enc_w[hh*O + o] * dec_w[o*H + k];
    M[hh*H + k] = s;
}

__global__ __launch_bounds__(256) void k_cd(
    const float* __restrict__ w_ih0,
    const float* __restrict__ nxt0, const float* __restrict__ d,
    float* __restrict__ x0c, float* __restrict__ cd)
{
    int j = blockIdx.x * 256 + threadIdx.x;
    const float* row = w_ih0 + (size_t)j * (H + PP);
    float sA = 0.f, sB = 0.f;
    for (int k = 0; k < H; ++k) { float w = row[k]; sA += w * nxt0[k]; sB += w * d[k]; }
    x0c[j] = sA; cd[j] = sB;
}

__global__ __launch_bounds__(256) void k_W0eff(
    const float* __restrict__ w_ih0, const float* __restrict__ M,
    float* __restrict__ W0eff)
{
    int k0 = (threadIdx.x & 127) * 4;
    int jsub = threadIdx.x >> 7;
    int j0 = blockIdx.x * 16 + jsub * 8;
    float4 a[8];
    #pragma unroll
    for (int i = 0; i < 8; ++i) a[i] = make_float4(0.f, 0.f, 0.f, 0.f);
    for (int hh = 0; hh < H; ++hh) {
        float4 mv = *(const float4*)(M + (size_t)hh * H + k0);
        #pragma unroll
        for (int i = 0; i < 8; ++i) {
            float w = w_ih0[(size_t)(j0 + i) * (H + PP) + hh];
            a[i].x += w * mv.x; a[i].y += w * mv.y;
            a[i].z += w * mv.z; a[i].w += w * mv.w;
        }
    }
    #pragma unroll
    for (int i = 0; i < 8; ++i)
        *(float4*)(W0eff + (size_t)(j0 + i) * H + k0) = a[i];
}

__global__ __launch_bounds__(256) void k_bias(
    const float* __restrict__ w_ih0, const float* __restrict__ props,
    const float* __restrict__ b_ih0, const float* __restrict__ b_hh0,
    const float* __restrict__ x0c, const float* __restrict__ cd,
    float* __restrict__ biasA, float* __restrict__ biasB)
{
    int idx = blockIdx.x * 256 + threadIdx.x;
    int j = idx >> 7, b = idx & 127;
    const float* wp = w_ih0 + (size_t)j * (H + PP) + H;
    const float* pr = props + b * PP;
    float pc = wp[0]*pr[0] + wp[1]*pr[1] + wp[2]*pr[2] + wp[3]*pr[3];
    float base = b_ih0[j] + b_hh0[j] + pc;
    biasA[idx] = base + x0c[j];
    biasB[idx] = base + cd[j];
}

// ---- shared device helpers for the persistent kernels ----------------------

__device__ __forceinline__ void stage_weights(
    unsigned int* sWH, float* sBias, unsigned int* sDecH, float* sBL,
    const RnnParams& p, int wg, int u0, int tid, bool isdec)
{
    const float* bases[6] = { p.W0eff, p.w_hh0, p.w_ihr, p.w_hhr,
                              p.w_ihr + GH, p.w_hhr + GH };
    #pragma unroll
    for (int s = 0; s < 6; ++s) {
        for (int idx = tid; idx < 2048; idx += 512) {
            int r = idx >> 8, kp = idx & 255;
            int j = (r >> 1) * H + u0 + (r & 1);
            const float* src = bases[s] + (size_t)j * H + 2*kp;
            sWH[s*2048 + (r << 8) + kp] = pack2h(src[0], src[1]);
        }
    }
    for (int idx = tid; idx < 2048; idx += 512) {
        int pl = idx >> 10, r = (idx >> 7) & 7, b = idx & 127;
        int j = (r >> 1) * H + u0 + (r & 1);
        sBias[idx] = (pl ? p.biasB : p.biasA)[(size_t)j * B + b];
    }
    if (tid < 16) {
        int l = tid >> 3, r = tid & 7;
        int j = (r >> 1) * H + u0 + (r & 1);
        sBL[tid] = p.b_ihr[l*G + j] + p.b_hhr[l*G + j];
    }
    if (isdec && tid < 256) {
        const float* src = p.dec_w + (size_t)wg * H + 2*tid;
        sDecH[tid] = pack2h(src[0], src[1]);
    }
}

// ===========================================================================
// PATH A kernel: h-part hoisted above the barrier; flat arrive-flag barrier
// ===========================================================================

__global__ __launch_bounds__(512, 2) void rnn_persistent_a(RnnParams p)
{
    extern __shared__ float sm[];
    const int tid   = threadIdx.x;
    const int wg    = blockIdx.x;       // owns units 2wg,2wg+1 == k-pair wg
    const int u0    = wg * 2;
    const int b4    = tid & 31;         // batches 4b4..4b4+3
    const int khalf = (tid >> 5) & 1;   // folded by shfl_xor(32)
    const int ks    = tid >> 6;         // wave [0,8)

    unsigned int* sWH   = (unsigned int*)(sm + SM_WH);
    float*        sBias = sm + SM_BIAS;
    unsigned int* sDecH = (unsigned int*)(sm + SM_DECH);
    float*        sBL   = sm + SM_BL;
    float*        sG    = sm + SM_G;    // [8r][8ks][32b4] x4
    float*        sDb   = sm + SM_DB;   // [8ks][32b4] x4
    float*        sH    = sm + SM_H;

    float* c0 = p.c; float* c1 = p.c + HB; float* c2 = p.c + 2*HB;
    const bool  isdec = (wg < O);
    const float decb  = isdec ? p.dec_b[wg] : 0.f;

    // one-time invalidate of pre-launch (poison-era) clean lines
    __builtin_amdgcn_fence(__ATOMIC_ACQUIRE, "agent");

    stage_weights(sWH, sBias, sDecH, sBL, p, wg, u0, tid, isdec);
    __syncthreads();

    unsigned int done = 0;              // barriers completed (arrives issued)
    unsigned int* arrive = p.arrive;

    // flat barrier: every WG's first 256 threads poll all 256 arrive flags.
    auto bar_wait = [&]() {
        if (tid < 256) {
            while (__hip_atomic_load(&arrive[(size_t)tid * 16],
                    __ATOMIC_RELAXED, __HIP_MEMORY_SCOPE_AGENT) < done)
                __builtin_amdgcn_s_sleep(1);
        }
        __syncthreads();
    };
    auto bar_arrive = [&]() {
        __syncthreads();    // drain h stores (compiler emits vmcnt(0) here)
        if (tid == 0)
            __hip_atomic_fetch_add(&arrive[(size_t)wg * 16], 1u,
                                   __ATOMIC_RELEASE, __HIP_MEMORY_SCOPE_AGENT);
        ++done;
    };

    auto slot = [&](int l, int s) -> unsigned int* {
        return p.h + ((size_t)(l * NSLOT + s) << 15);
    };

    const int kp0 = ks * 32 + khalf * 16;
    const int xo  = 4 * b4;

    float4 acc[8];

    // h-part: consumes state 3 barriers old => runs BEFORE bar_wait.
    auto h_part = [&](const unsigned int* __restrict__ hs, int ph) {
        #pragma unroll
        for (int r = 0; r < 8; ++r) acc[r] = make_float4(0.f, 0.f, 0.f, 0.f);
        const unsigned int* wh = sWH + (ph*2 + 1) * 2048;
        for (int kp = kp0; kp < kp0 + 16; kp += 4) {
            uint4 x0 = *(const uint4*)(hs + (kp+0)*128 + xo);
            uint4 x1 = *(const uint4*)(hs + (kp+1)*128 + xo);
            uint4 x2 = *(const uint4*)(hs + (kp+2)*128 + xo);
            uint4 x3 = *(const uint4*)(hs + (kp+3)*128 + xo);
            #pragma unroll
            for (int r = 0; r < 8; ++r) {
                uint4 wq = *(const uint4*)(wh + r*256 + kp);
                acc[r].x = FDOT2(wq.x, x0.x, acc[r].x); acc[r].y = FDOT2(wq.x, x0.y, acc[r].y);
                acc[r].z = FDOT2(wq.x, x0.z, acc[r].z); acc[r].w = FDOT2(wq.x, x0.w, acc[r].w);
                acc[r].x = FDOT2(wq.y, x1.x, acc[r].x); acc[r].y = FDOT2(wq.y, x1.y, acc[r].y);
                acc[r].z = FDOT2(wq.y, x1.z, acc[r].z); acc[r].w = FDOT2(wq.y, x1.w, acc[r].w);
                acc[r].x = FDOT2(wq.z, x2.x, acc[r].x); acc[r].y = FDOT2(wq.z, x2.y, acc[r].y);
                acc[r].z = FDOT2(wq.z, x2.z, acc[r].z); acc[r].w = FDOT2(wq.z, x2.w, acc[r].w);
                acc[r].x = FDOT2(wq.w, x3.x, acc[r].x); acc[r].y = FDOT2(wq.w, x3.y, acc[r].y);
                acc[r].z = FDOT2(wq.w, x3.z, acc[r].z); acc[r].w = FDOT2(wq.w, x3.w, acc[r].w);
            }
        }
    };

    // x-part + epilogue + store (after bar_wait)
    auto x_part_finish = [&](const unsigned int* __restrict__ xs, int ph,
                             const float* biasPlane, const float* biasScal,
                             float* cc, unsigned int* hout,
                             bool dopig, float* dout) {
        float4 accd = make_float4(0.f, 0.f, 0.f, 0.f);
        const unsigned int* wx = sWH + (ph*2 + 0) * 2048;
        for (int kp = kp0; kp < kp0 + 16; kp += 4) {
            uint4 x0 = *(const uint4*)(xs + (kp+0)*128 + xo);
            uint4 x1 = *(const uint4*)(xs + (kp+1)*128 + xo);
            uint4 x2 = *(const uint4*)(xs + (kp+2)*128 + xo);
            uint4 x3 = *(const uint4*)(xs + (kp+3)*128 + xo);
            #pragma unroll
            for (int r = 0; r < 8; ++r) {
                uint4 wq = *(const uint4*)(wx + r*256 + kp);
                acc[r].x = FDOT2(wq.x, x0.x, acc[r].x); acc[r].y = FDOT2(wq.x, x0.y, acc[r].y);
                acc[r].z = FDOT2(wq.x, x0.z, acc[r].z); acc[r].w = FDOT2(wq.x, x0.w, acc[r].w);
                acc[r].x = FDOT2(wq.y, x1.x, acc[r].x); acc[r].y = FDOT2(wq.y, x1.y, acc[r].y);
                acc[r].z = FDOT2(wq.y, x1.z, acc[r].z); acc[r].w = FDOT2(wq.y, x1.w, acc[r].w);
                acc[r].x = FDOT2(wq.z, x2.x, acc[r].x); acc[r].y = FDOT2(wq.z, x2.y, acc[r].y);
                acc[r].z = FDOT2(wq.z, x2.z, acc[r].z); acc[r].w = FDOT2(wq.z, x2.w, acc[r].w);
                acc[r].x = FDOT2(wq.w, x3.x, acc[r].x); acc[r].y = FDOT2(wq.w, x3.y, acc[r].y);
                acc[r].z = FDOT2(wq.w, x3.z, acc[r].z); acc[r].w = FDOT2(wq.w, x3.w, acc[r].w);
            }
            if (dopig) {
                uint4 dq = *(const uint4*)(sDecH + kp);
                accd.x = FDOT2(dq.x, x0.x, accd.x); accd.y = FDOT2(dq.x, x0.y, accd.y);
                accd.z = FDOT2(dq.x, x0.z, accd.z); accd.w = FDOT2(dq.x, x0.w, accd.w);
                accd.x = FDOT2(dq.y, x1.x, accd.x); accd.y = FDOT2(dq.y, x1.y, accd.y);
                accd.z = FDOT2(dq.y, x1.z, accd.z); accd.w = FDOT2(dq.y, x1.w, accd.w);
                accd.x = FDOT2(dq.z, x2.x, accd.x); accd.y = FDOT2(dq.z, x2.y, accd.y);
                accd.z = FDOT2(dq.z, x2.z, accd.z); accd.w = FDOT2(dq.z, x2.w, accd.w);
                accd.x = FDOT2(dq.w, x3.x, accd.x); accd.y = FDOT2(dq.w, x3.y, accd.y);
                accd.z = FDOT2(dq.w, x3.z, accd.z); accd.w = FDOT2(dq.w, x3.w, accd.w);
            }
        }

        #pragma unroll
        for (int r = 0; r < 8; ++r) {
            acc[r].x += __shfl_xor(acc[r].x, 32, 64);
            acc[r].y += __shfl_xor(acc[r].y, 32, 64);
            acc[r].z += __shfl_xor(acc[r].z, 32, 64);
            acc[r].w += __shfl_xor(acc[r].w, 32, 64);
        }
        if (khalf == 0) {
            #pragma unroll
            for (int r = 0; r < 8; ++r)
                *(float4*)(sG + ((r*8 + ks)*32 + b4)*4) = acc[r];
        }
        if (dopig) {
            accd.x += __shfl_xor(accd.x, 32, 64);
            accd.y += __shfl_xor(accd.y, 32, 64);
            accd.z += __shfl_xor(accd.z, 32, 64);
            accd.w += __shfl_xor(accd.w, 32, 64);
            if (khalf == 0) *(float4*)(sDb + (ks*32 + b4)*4) = accd;
        }
        __syncthreads();

        if (tid < 256) {
            int mi = tid >> 7, b = tid & 127;
            float g[4];
            #pragma unroll
            for (int q = 0; q < 4; ++q) {
                int r = q*2 + mi;
                float s = biasPlane ? biasPlane[r*128 + b] : biasScal[r];
                #pragma unroll
                for (int k2 = 0; k2 < 8; ++k2)
                    s += sG[((r*8 + k2)*32 + (b >> 2))*4 + (b & 3)];
                g[q] = s;
            }
            float ig = 1.f/(1.f+expf(-g[0]));
            float fg = 1.f/(1.f+expf(-g[1]));
            float gv = tanhf(g[2]);
            float og = 1.f/(1.f+expf(-g[3]));
            int idx = (u0 + mi)*B + b;
            float cn = fg*cc[idx] + ig*gv;
            cc[idx] = cn;
            sH[mi*128 + b] = og*tanhf(cn);
        } else if (dopig && tid < 384) {
            int b = tid - 256;
            float s = decb;
            #pragma unroll
            for (int k2 = 0; k2 < 8; ++k2)
                s += sDb[(k2*32 + (b >> 2))*4 + (b & 3)];
            dout[(size_t)b * (T*O)] = s;
        }
        __syncthreads();
        if (tid < 64) {                       // pack k-pair x 2 batches -> 8B
            int b0 = tid * 2;
            uint2 v;
            v.x = pack2h(sH[b0],     sH[128 + b0]);
            v.y = pack2h(sH[b0 + 1], sH[128 + b0 + 1]);
            cstore_u2(hout + wg*128 + b0, v);   // agent store -> IF
        }
    };

    for (int t = 0; t < T; ++t) {
        bool pig = (t > 0) && isdec;
        // phase L0
        h_part(slot(0, t), 0);
        bar_wait();
        x_part_finish(slot(2, t), 0, sBias + (t == 0 ? 0 : 1024), nullptr,
                      c0, slot(0, t+1), pig,
                      pig ? (p.out + (size_t)(t-1)*O + wg) : nullptr);
        bar_arrive();
        // phase L1
        h_part(slot(1, t), 1);
        bar_wait();
        x_part_finish(slot(0, t+1), 1, nullptr, sBL, c1, slot(1, t+1),
                      false, nullptr);
        bar_arrive();
        // phase L2
        h_part(slot(2, t), 2);
        bar_wait();
        x_part_finish(slot(1, t+1), 2, nullptr, sBL + 8, c2, slot(2, t+1),
                      false, nullptr);
        bar_arrive();
    }

    // final logits from slot(2, 64) — must wait for last barrier first
    bar_wait();
    if (isdec) {
        const unsigned int* xs = slot(2, T);
        float4 accd = make_float4(0.f, 0.f, 0.f, 0.f);
        for (int kp = kp0; kp < kp0 + 16; kp += 4) {
            uint4 x0 = *(const uint4*)(xs + (kp+0)*128 + xo);
            uint4 x1 = *(const uint4*)(xs + (kp+1)*128 + xo);
            uint4 x2 = *(const uint4*)(xs + (kp+2)*128 + xo);
            uint4 x3 = *(const uint4*)(xs + (kp+3)*128 + xo);
            uint4 dq = *(const uint4*)(sDecH + kp);
            accd.x = FDOT2(dq.x, x0.x, accd.x); accd.y = FDOT2(dq.x, x0.y, accd.y);
            accd.z = FDOT2(dq.x, x0.z, accd.z); accd.w = FDOT2(dq.x, x0.w, accd.w);
            accd.x = FDOT2(dq.y, x1.x, accd.x); accd.y = FDOT2(dq.y, x1.y, accd.y);
            accd.z = FDOT2(dq.y, x1.z, accd.z); accd.w = FDOT2(dq.y, x1.w, accd.w);
            accd.x = FDOT2(dq.z, x2.x, accd.x); accd.y = FDOT2(dq.z, x2.y, accd.y);
            accd.z = FDOT2(dq.z, x2.z, accd.z); accd.w = FDOT2(dq.z, x2.w, accd.w);
            accd.x = FDOT2(dq.w, x3.x, accd.x); accd.y = FDOT2(dq.w, x3.y, accd.y);
            accd.z = FDOT2(dq.w, x3.z, accd.z); accd.w = FDOT2(dq.w, x3.w, accd.w);
        }
        accd.x += __shfl_xor(accd.x, 32, 64);
        accd.y += __shfl_xor(accd.y, 32, 64);
        accd.z += __shfl_xor(accd.z, 32, 64);
        accd.w += __shfl_xor(accd.w, 32, 64);
        if (khalf == 0) *(float4*)(sDb + (ks*32 + b4)*4) = accd;
    }
    __syncthreads();
    if (isdec && tid < 128) {
        int b = tid;
        float s = decb;
        #pragma unroll
        for (int k2 = 0; k2 < 8; ++k2)
            s += sDb[(k2*32 + (b >> 2))*4 + (b & 3)];
        p.out[((size_t)b * T + 63) * O + wg] = s;
    }
}

// ===========================================================================
// PATH B kernel: round-9 (proven 2.45 ms) — agent 8B loads, ping-pong state
// ===========================================================================

__global__ __launch_bounds__(512, 2) void rnn_persistent_b(RnnParams p)
{
    extern __shared__ float sm[];
    const int tid = threadIdx.x;
    const int wg  = blockIdx.x;
    const int u0  = wg * 2;
    const int b2  = tid & 63;
    const int ks  = tid >> 6;

    unsigned int* sWH   = (unsigned int*)(sm + SM_WH);
    float*        sBias = sm + SM_BIAS;
    unsigned int* sDecH = (unsigned int*)(sm + SM_DECH);
    float*        sBL   = sm + SM_BL;
    float2*       sGbuf = (float2*)(sm + SM_G);
    float2*       sDecb = (float2*)(sm + SM_DB);
    float*        sH    = sm + SM_H;

    unsigned int* h0p = p.h + 0*32768; unsigned int* h0c = p.h + 1*32768;
    unsigned int* h1p = p.h + 2*32768; unsigned int* h1c = p.h + 3*32768;
    unsigned int* h2p = p.h + 4*32768; unsigned int* h2c = p.h + 5*32768;
    float* c0 = p.c; float* c1 = p.c + HB; float* c2 = p.c + 2*HB;

    const bool  isdec = (wg < O);
    const float decb  = isdec ? p.dec_b[wg] : 0.f;

    stage_weights(sWH, sBias, sDecH, sBL, p, wg, u0, tid, isdec);
    __syncthreads();

    unsigned int epoch = 0;
    unsigned int* arrive = p.arrive;
    unsigned int* gocnt  = p.gocnt;
    auto gbar = [&]() {
        ++epoch;
        __syncthreads();
        if (tid == 0)
            __hip_atomic_fetch_add(&arrive[(size_t)wg * 16], 1u,
                                   __ATOMIC_RELEASE, __HIP_MEMORY_SCOPE_AGENT);
        if (wg == 0) {
            if (tid < 256) {
                while (__hip_atomic_load(&arrive[(size_t)tid * 16],
                        __ATOMIC_RELAXED, __HIP_MEMORY_SCOPE_AGENT) < epoch)
                    __builtin_amdgcn_s_sleep(1);
            }
            __syncthreads();
            if (tid == 0)
                __hip_atomic_fetch_add(gocnt, 1u,
                                       __ATOMIC_RELEASE, __HIP_MEMORY_SCOPE_AGENT);
        }
        if (tid == 0) {
            while (__hip_atomic_load(gocnt, __ATOMIC_RELAXED,
                                     __HIP_MEMORY_SCOPE_AGENT) < epoch)
                __builtin_amdgcn_s_sleep(1);
        }
        __syncthreads();
    };

    auto phase = [&](const unsigned int* __restrict__ xs,
                     const unsigned int* __restrict__ hs,
                     int ph, const float* biasPlane, const float* biasScal,
                     float* cc, unsigned int* hout, bool dopig, float* dout) {
        float2 acc[8];
        #pragma unroll
        for (int r = 0; r < 8; ++r) { acc[r].x = 0.f; acc[r].y = 0.f; }
        float2 accd; accd.x = 0.f; accd.y = 0.f;

        const unsigned int* wx = sWH + (ph*2 + 0) * 2048;
        const unsigned int* wh = sWH + (ph*2 + 1) * 2048;
        const int kb = ks * 32;
        const int xo = 2 * b2;

        for (int kp = kb; kp < kb + 32; kp += 4) {
            uint2 x0 = cload_u2(xs + (kp+0)*128 + xo);
            uint2 x1 = cload_u2(xs + (kp+1)*128 + xo);
            uint2 x2 = cload_u2(xs + (kp+2)*128 + xo);
            uint2 x3 = cload_u2(xs + (kp+3)*128 + xo);
            if (dopig) {
                uint4 dq = *(const uint4*)(sDecH + kp);
                accd.x = FDOT2(dq.x, x0.x, accd.x); accd.y = FDOT2(dq.x, x0.y, accd.y);
                accd.x = FDOT2(dq.y, x1.x, accd.x); accd.y = FDOT2(dq.y, x1.y, accd.y);
                accd.x = FDOT2(dq.z, x2.x, accd.x); accd.y = FDOT2(dq.z, x2.y, accd.y);
                accd.x = FDOT2(dq.w, x3.x, accd.x); accd.y = FDOT2(dq.w, x3.y, accd.y);
            }
            #pragma unroll
            for (int r = 0; r < 8; ++r) {
                uint4 wq = *(const uint4*)(wx + r*256 + kp);
                acc[r].x = FDOT2(wq.x, x0.x, acc[r].x); acc[r].y = FDOT2(wq.x, x0.y, acc[r].y);
                acc[r].x = FDOT2(wq.y, x1.x, acc[r].x); acc[r].y = FDOT2(wq.y, x1.y, acc[r].y);
                acc[r].x = FDOT2(wq.z, x2.x, acc[r].x); acc[r].y = FDOT2(wq.z, x2.y, acc[r].y);
                acc[r].x = FDOT2(wq.w, x3.x, acc[r].x); acc[r].y = FDOT2(wq.w, x3.y, acc[r].y);
            }
        }
        for (int kp = kb; kp < kb + 32; kp += 4) {
            uint2 x0 = cload_u2(hs + (kp+0)*128 + xo);
            uint2 x1 = cload_u2(hs + (kp+1)*128 + xo);
            uint2 x2 = cload_u2(hs + (kp+2)*128 + xo);
            uint2 x3 = cload_u2(hs + (kp+3)*128 + xo);
            #pragma unroll
            for (int r = 0; r < 8; ++r) {
                uint4 wq = *(const uint4*)(wh + r*256 + kp);
                acc[r].x = FDOT2(wq.x, x0.x, acc[r].x); acc[r].y = FDOT2(wq.x, x0.y, acc[r].y);
                acc[r].x = FDOT2(wq.y, x1.x, acc[r].x); acc[r].y = FDOT2(wq.y, x1.y, acc[r].y);
                acc[r].x = FDOT2(wq.z, x2.x, acc[r].x); acc[r].y = FDOT2(wq.z, x2.y, acc[r].y);
                acc[r].x = FDOT2(wq.w, x3.x, acc[r].x); acc[r].y = FDOT2(wq.w, x3.y, acc[r].y);
            }
        }

        #pragma unroll
        for (int r = 0; r < 8; ++r) sGbuf[(r*8 + ks)*64 + b2] = acc[r];
        if (dopig) sDecb[ks*64 + b2] = accd;
        __syncthreads();

        if (tid < 256) {
            int mi = tid >> 7, b = tid & 127;
            float g[4];
            #pragma unroll
            for (int q = 0; q < 4; ++q) {
                int r = q*2 + mi;
                float s = biasPlane ? biasPlane[r*128 + b] : biasScal[r];
                #pragma unroll
                for (int k2 = 0; k2 < 8; ++k2) {
                    float2 v = sGbuf[(r*8 + k2)*64 + (b >> 1)];
                    s += (b & 1) ? v.y : v.x;
                }
                g[q] = s;
            }
            float ig = 1.f/(1.f+expf(-g[0]));
            float fg = 1.f/(1.f+expf(-g[1]));
            float gv = tanhf(g[2]);
            float og = 1.f/(1.f+expf(-g[3]));
            int idx = (u0 + mi)*B + b;
            float cn = fg*cc[idx] + ig*gv;
            cc[idx] = cn;
            sH[mi*128 + b] = og*tanhf(cn);
        } else if (dopig && tid < 384) {
            int b = tid - 256;
            float s = decb;
            #pragma unroll
            for (int k2 = 0; k2 < 8; ++k2) {
                float2 v = sDecb[k2*64 + (b >> 1)];
                s += (b & 1) ? v.y : v.x;
            }
            dout[(size_t)b * (T*O)] = s;
        }
        __syncthreads();
        if (tid < 64) {
            int b0 = tid * 2;
            uint2 v;
            v.x = pack2h(sH[b0],     sH[128 + b0]);
            v.y = pack2h(sH[b0 + 1], sH[128 + b0 + 1]);
            cstore_u2(hout + wg*128 + b0, v);
        }
    };

    for (int t = 0; t < T; ++t) {
        bool pig = (t > 0) && isdec;
        phase(h2p, h0p, 0, sBias + (t == 0 ? 0 : 1024), nullptr,
              c0, h0c, pig, pig ? (p.out + (size_t)(t-1)*O + wg) : nullptr);
        gbar();
        phase(h0c, h1p, 1, nullptr, sBL, c1, h1c, false, nullptr);
        gbar();
        phase(h1c, h2p, 2, nullptr, sBL + 8, c2, h2c, false, nullptr);
        gbar();
        unsigned int* tp;
        tp = h0p; h0p = h0c; h0c = tp;
        tp = h1p; h1p = h1c; h1c = tp;
        tp = h2p; h2p = h2c; h2c = tp;
    }

    if (isdec) {
        float2 accd; accd.x = 0.f; accd.y = 0.f;
        const int kb = ks * 32;
        const int xo = 2 * b2;
        for (int kp = kb; kp < kb + 32; kp += 4) {
            uint2 x0 = cload_u2(h2p + (kp+0)*128 + xo);
            uint2 x1 = cload_u2(h2p + (kp+1)*128 + xo);
            uint2 x2 = cload_u2(h2p + (kp+2)*128 + xo);
            uint2 x3 = cload_u2(h2p + (kp+3)*128 + xo);
            uint4 dq = *(const uint4*)(sDecH + kp);
            accd.x = FDOT2(dq.x, x0.x, accd.x); accd.y = FDOT2(dq.x, x0.y, accd.y);
            accd.x = FDOT2(dq.y, x1.x, accd.x); accd.y = FDOT2(dq.y, x1.y, accd.y);
            accd.x = FDOT2(dq.z, x2.x, accd.x); accd.y = FDOT2(dq.z, x2.y, accd.y);
            accd.x = FDOT2(dq.w, x3.x, accd.x); accd.y = FDOT2(dq.w, x3.y, accd.y);
        }
        sDecb[ks*64 + b2] = accd;
    }
    __syncthreads();
    if (isdec && tid < 128) {
        int b = tid;
        float s = decb;
        #pragma unroll
        for (int k2 = 0; k2 < 8; ++k2) {
            float2 v = sDecb[k2*64 + (b >> 1)];
            s += (b & 1) ? v.y : v.x;
        }
        p.out[((size_t)b * T + 63) * O + wg] = s;
    }
}

// ===========================================================================
// LEGACY FALLBACK (round-0, proven correct)
// ===========================================================================

__global__ __launch_bounds__(256) void init_kernel(
    const float* __restrict__ enc_w, const float* __restrict__ enc_b,
    float* __restrict__ nxtT, float* __restrict__ hbufs, float* __restrict__ cbufs)
{
    int idx = blockIdx.x * 256 + threadIdx.x;
    #pragma unroll
    for (int i = 0; i < 6; ++i) hbufs[i * HB + idx] = 0.f;
    #pragma unroll
    for (int i = 0; i < 3; ++i) cbufs[i * HB + idx] = 0.f;
    int h = idx >> 7;
    nxtT[idx] = enc_w[h * O + 1] + enc_b[h];
}

__global__ __launch_bounds__(256) void transpose_kernel(
    const float* __restrict__ dec_w, const float* __restrict__ enc_w,
    float* __restrict__ dec_wT, float* __restrict__ enc_wT)
{
    int idx = blockIdx.x * 256 + threadIdx.x;
    if (idx < O * H) {
        int o = idx / H, k = idx - o * H;
        dec_wT[k * O + o] = dec_w[o * H + k];
        enc_wT[o * H + k] = enc_w[k * O + o];
    }
}

__global__ __launch_bounds__(512) void gates_kernel(
    const float* __restrict__ xT, const float* __restrict__ hT,
    const float* __restrict__ w_ih, int ldih,
    const float* __restrict__ w_hh,
    const float* __restrict__ b_ih, const float* __restrict__ b_hh,
    const float* __restrict__ props,
    float* __restrict__ c, float* __restrict__ hout)
{
    const int wg = blockIdx.x;
    const int bg = wg >> 7, jg = wg & 127;
    const int m0 = jg * 4;
    const int lane_b = threadIdx.x & 63, ks = threadIdx.x >> 6;
    const int bb = (bg << 6) + lane_b;
    float acc[16];
    #pragma unroll
    for (int r = 0; r < 16; ++r) acc[r] = 0.f;
    const float* wih_rows[16]; const float* whh_rows[16];
    #pragma unroll
    for (int q = 0; q < 4; ++q)
        #pragma unroll
        for (int mi = 0; mi < 4; ++mi) {
            int r = q * 4 + mi, j = q * H + m0 + mi;
            wih_rows[r] = w_ih + (size_t)j * ldih;
            whh_rows[r] = w_hh + (size_t)j * H;
        }
    const int kbeg = ks * 64, kend = ks * 64 + 64;
    for (int k0 = kbeg; k0 < kend; k0 += 4) {
        float x0 = xT[(k0+0)*B+bb], x1 = xT[(k0+1)*B+bb];
        float x2 = xT[(k0+2)*B+bb], x3 = xT[(k0+3)*B+bb];
        #pragma unroll
        for (int r = 0; r < 16; ++r) {
            float4 wv = *(const float4*)(wih_rows[r] + k0);
            acc[r] += wv.x*x0 + wv.y*x1 + wv.z*x2 + wv.w*x3;
        }
    }
    for (int k0 = kbeg; k0 < kend; k0 += 4) {
        float x0 = hT[(k0+0)*B+bb], x1 = hT[(k0+1)*B+bb];
        float x2 = hT[(k0+2)*B+bb], x3 = hT[(k0+3)*B+bb];
        #pragma unroll
        for (int r = 0; r < 16; ++r) {
            float4 wv = *(const float4*)(whh_rows[r] + k0);
            acc[r] += wv.x*x0 + wv.y*x1 + wv.z*x2 + wv.w*x3;
        }
    }
    __shared__ float gbuf[16][8][64];
    #pragma unroll
    for (int r = 0; r < 16; ++r) gbuf[r][ks][lane_b] = acc[r];
    __syncthreads();
    if (threadIdx.x < 256) {
        int mi = threadIdx.x >> 6, b = threadIdx.x & 63;
        int bbo = (bg << 6) + b, m = m0 + mi;
        float g[4];
        #pragma unroll
        for (int q = 0; q < 4; ++q) {
            int j = q * H + m;
            float s = b_ih[j] + b_hh[j];
            #pragma unroll
            for (int k2 = 0; k2 < 8; ++k2) s += gbuf[q*4+mi][k2][b];
            if (props) {
                const float* wp = w_ih + (size_t)j * ldih + H;
                const float* pp = props + bbo * PP;
                s += wp[0]*pp[0] + wp[1]*pp[1] + wp[2]*pp[2] + wp[3]*pp[3];
            }
            g[q] = s;
        }
        float ig = 1.f/(1.f+expf(-g[0]));
        float fg = 1.f/(1.f+expf(-g[1]));
        float gv = tanhf(g[2]);
        float og = 1.f/(1.f+expf(-g[3]));
        int idx = m * B + bbo;
        float cn = fg * c[idx] + ig * gv;
        c[idx] = cn;
        hout[idx] = og * tanhf(cn);
    }
}

__global__ __launch_bounds__(256) void decenc_kernel(
    const float* __restrict__ h2T, const float* __restrict__ dec_wT,
    const float* __restrict__ dec_b, const float* __restrict__ enc_wT,
    const float* __restrict__ enc_b, float* __restrict__ nxtT,
    float* __restrict__ out, int t)
{
    const int b = blockIdx.x;
    const int w = threadIdx.x >> 6, o = threadIdx.x & 63;
    __shared__ float red[4][64];
    __shared__ float lg[64];
    float p = 0.f;
    if (o < O)
        for (int k = w * 128; k < w * 128 + 128; ++k)
            p += h2T[k * B + b] * dec_wT[k * O + o];
    red[w][o] = p;
    __syncthreads();
    if (threadIdx.x < 64) {
        int oo = threadIdx.x;
        float s = 0.f;
        if (oo < O) {
            s = dec_b[oo] + red[0][oo] + red[1][oo] + red[2][oo] + red[3][oo];
            out[((size_t)b * T + t) * O + oo] = s;
        }
        lg[oo] = s;
    }
    __syncthreads();
    for (int h = threadIdx.x; h < H; h += 256) {
        float s = enc_b[h];
        #pragma unroll 1
        for (int oo = 0; oo < O; ++oo) s += lg[oo] * enc_wT[oo * H + h];
        nxtT[h * B + b] = s;
    }
}

// ===========================================================================
extern "C" void kernel_launch(void* const* d_in, const int* in_sizes, int n_in,
                              void* d_out, int out_size, void* d_ws, size_t ws_size,
                              hipStream_t stream) {
    const float* props = (const float*)d_in[1];
    const float* enc_w = (const float*)d_in[2];
    const float* enc_b = (const float*)d_in[3];
    const float* dec_w = (const float*)d_in[4];
    const float* dec_b = (const float*)d_in[5];
    const float* w_ih0 = (const float*)d_in[6];
    const float* w_hh0 = (const float*)d_in[7];
    const float* b_ih0 = (const float*)d_in[8];
    const float* b_hh0 = (const float*)d_in[9];
    const float* w_ihr = (const float*)d_in[10];
    const float* w_hhr = (const float*)d_in[11];
    const float* b_ihr = (const float*)d_in[12];
    const float* b_hhr = (const float*)d_in[13];

    float* ws = (float*)d_ws;
    const size_t NEED_B = ((size_t)34 * HB + 5120 + 4160) * sizeof(float);
    const size_t LDS_BYTES = (size_t)SM_TOTAL * sizeof(float);

    static int lds_a = -1, lds_b = -1;
    if (lds_a < 0) {
        lds_a = (hipFuncSetAttribute((const void*)rnn_persistent_a,
                  hipFuncAttributeMaxDynamicSharedMemorySize,
                  (int)LDS_BYTES) == hipSuccess) ? 1 : 0;
        lds_b = (hipFuncSetAttribute((const void*)rnn_persistent_b,
                  hipFuncAttributeMaxDynamicSharedMemorySize,
                  (int)LDS_BYTES) == hipSuccess) ? 1 : 0;
    }

    if (ws_size >= NEED_A && lds_a == 1) {
        // ---- PATH A: time-indexed slots, h-part hoist, flat barrier ----
        unsigned int* hbuf = (unsigned int*)ws;
        float* cbuf  = ws + OFF_C;
        float* M     = ws + OFF_M;
        float* W0eff = ws + OFF_W0;
        float* biasA = ws + OFF_BA;
        float* biasB = ws + OFF_BB;
        float* dvec  = ws + OFF_DV;
        float* nxt0  = dvec + 512;
        float* x0c   = nxt0 + 512;
        float* cd    = x0c + 2048;
        unsigned int* barptr = (unsigned int*)(ws + OFF_BAR);

        k_init_a<<<256, 256, 0, stream>>>(enc_w, enc_b, dec_b, hbuf, cbuf,
                                          dvec, nxt0, barptr);
        k_M<<<1024, 256, 0, stream>>>(enc_w, dec_w, M);
        k_cd<<<8, 256, 0, stream>>>(w_ih0, nxt0, dvec, x0c, cd);
        k_W0eff<<<128, 256, 0, stream>>>(w_ih0, M, W0eff);
        k_bias<<<1024, 256, 0, stream>>>(w_ih0, props, b_ih0, b_hh0, x0c, cd,
                                         biasA, biasB);

        RnnParams prm;
        prm.w_hh0 = w_hh0; prm.w_ihr = w_ihr; prm.w_hhr = w_hhr;
        prm.b_ihr = b_ihr; prm.b_hhr = b_hhr;
        prm.dec_w = dec_w; prm.dec_b = dec_b;
        prm.W0eff = W0eff; prm.biasA = biasA; prm.biasB = biasB;
        prm.h = hbuf; prm.c = cbuf; prm.out = (float*)d_out;
        prm.arrive = barptr; prm.gocnt = barptr + 4096;

        void* args[] = { &prm };
        hipLaunchCooperativeKernel((const void*)rnn_persistent_a,
                                   dim3(256), dim3(512), args,
                                   (unsigned int)LDS_BYTES, stream);
        return;
    }

    if (ws_size >= NEED_B && lds_b == 1) {
        // ---- PATH B: round-9 proven kernel ----
        unsigned int* hbuf = (unsigned int*)ws;
        float* cbuf  = ws + 3*HB;
        float* M     = ws + 6*HB;
        float* W0eff = ws + 10*HB;
        float* biasA = ws + 26*HB;
        float* biasB = ws + 30*HB;
        float* dvec  = ws + 34*HB;
        float* nxt0  = dvec + 512;
        float* x0c   = nxt0 + 512;
        float* cd    = x0c + 2048;
        unsigned int* barptr = (unsigned int*)(cd + 2048);

        k_init_b<<<256, 256, 0, stream>>>(enc_w, enc_b, dec_b, (float*)hbuf,
                                          cbuf, dvec, nxt0, barptr);
        k_M<<<1024, 256, 0, stream>>>(enc_w, dec_w, M);
        k_cd<<<8, 256, 0, stream>>>(w_ih0, nxt0, dvec, x0c, cd);
        k_W0eff<<<128, 256, 0, stream>>>(w_ih0, M, W0eff);
        k_bias<<<1024, 256, 0, stream>>>(w_ih0, props, b_ih0, b_hh0, x0c, cd,
                                         biasA, biasB);

        RnnParams prm;
        prm.w_hh0 = w_hh0; prm.w_ihr = w_ihr; prm.w_hhr = w_hhr;
        prm.b_ihr = b_ihr; prm.b_hhr = b_hhr;
        prm.dec_w = dec_w; prm.dec_b = dec_b;
        prm.W0eff = W0eff; prm.biasA = biasA; prm.biasB = biasB;
        prm.h = hbuf; prm.c = cbuf; prm.out = (float*)d_out;
        prm.arrive = barptr; prm.gocnt = barptr + 4096;

        void* args[] = { &prm };
        hipLaunchCooperativeKernel((const void*)rnn_persistent_b,
                                   dim3(256), dim3(512), args,
                                   (unsigned int)LDS_BYTES, stream);
        return;
    }

    // ---- legacy multi-launch fallback ----
    float* nxtT   = ws;
    float* hb     = ws + HB;
    float* cb     = ws + 7*HB;
    float* dec_wT = ws + 10*HB;
    float* enc_wT = dec_wT + H*O;

    init_kernel<<<256, 256, 0, stream>>>(enc_w, enc_b, nxtT, hb, cb);
    transpose_kernel<<<(O*H + 255)/256, 256, 0, stream>>>(dec_w, enc_w, dec_wT, enc_wT);

    float* hprev[3]; float* hcur[3];
    for (int l = 0; l < 3; ++l) { hprev[l] = hb + (2*l)*HB; hcur[l] = hb + (2*l+1)*HB; }

    for (int t = 0; t < T; ++t) {
        gates_kernel<<<256, 512, 0, stream>>>(nxtT, hprev[0], w_ih0, H+PP, w_hh0,
                                              b_ih0, b_hh0, props, cb, hcur[0]);
        gates_kernel<<<256, 512, 0, stream>>>(hcur[0], hprev[1], w_ihr, H, w_hhr,
                                              b_ihr, b_hhr, nullptr, cb + HB, hcur[1]);
        gates_kernel<<<256, 512, 0, stream>>>(hcur[1], hprev[2], w_ihr + (size_t)G*H, H,
                                              w_hhr + (size_t)G*H, b_ihr + G, b_hhr + G,
                                              nullptr, cb + 2*HB, hcur[2]);
        decenc_kernel<<<B, 256, 0, stream>>>(hcur[2], dec_wT, dec_b, enc_wT, enc_b,
                                             nxtT, (float*)d_out, t);
        for (int l = 0; l < 3; ++l) { float* tp = hprev[l]; hprev[l] = hcur[l]; hcur[l] = tp; }
    }
}

// Round 12
// 2342.292 us; speedup vs baseline: 1.9442x; 1.9442x over previous
//
#include <hip/hip_runtime.h>
#include <hip/hip_fp16.h>
#include <math.h>

// Problem dims (fixed by reference)
#define B 128
#define T 64
#define H 512
#define O 47
#define PP 4
#define G 2048         // 4*H
#define GH (G*H)
#define HB (H*B)       // 65536

// ===========================================================================
// PERSISTENT PATH A, round 12: r10-A + LDS-carried h-part hoist + early agg.
// ---------------------------------------------------------------------------
// r11 failed (4.5ms, 8.5GB HBM): (1) acc[8] float4 kept register-live across
// the barrier spin -> 128 B/thread/phase scratch spill (17MB FETCH + 26MB
// WRITE per phase); (2) flat barrier = 65536 pollers on 256 agent-scope
// lines flooded the ~600M trans/s IF path (variance 4.4->66ms).
// Fix, keeping the valid insight (h operand is 3 barriers old):
//  - h_part folds khalf and STORES PARTIALS TO sG BEFORE the spin; x_part
//    does same-thread RMW of sG afterward. No registers live across wait.
//  - r10's two-level barrier, split: bar_arrive = sync + arrive RMW, with
//    WG0 aggregating the 256 flags + posting go IMMEDIATELY (overlaps
//    everyone's h_part); bar_wait = tid0 polls go + sync. Poll population
//    identical to r10.
// Everything else = r10-A (proven 2323us): slot per (layer,t), plain 16B
// cached state loads, agent stores, fp16 weights in LDS + fdot2, entry-only
// acquire fence, launch_bounds(512,2), folding (r1).
// Fallbacks: r9 kernel (path B) if ws small; legacy multi-launch last.
// ===========================================================================

typedef _Float16 h16;
typedef _Float16 h16x2 __attribute__((ext_vector_type(2)));

__device__ __forceinline__ unsigned int pack2h(float a, float b) {
    union { unsigned int u; h16 h[2]; } c;
    c.h[0] = (h16)a; c.h[1] = (h16)b;
    return c.u;
}
__device__ __forceinline__ h16x2 as_h2(unsigned int u) {
    union { unsigned int u; h16x2 v; } c; c.u = u; return c.v;
}
__device__ __forceinline__ uint2 cload_u2(const unsigned int* p) {
    unsigned long long v = __hip_atomic_load((const unsigned long long*)p,
                                             __ATOMIC_RELAXED, __HIP_MEMORY_SCOPE_AGENT);
    union { unsigned long long u; uint2 w; } c; c.u = v; return c.w;
}
__device__ __forceinline__ void cstore_u2(unsigned int* p, uint2 v) {
    union { unsigned long long u; uint2 w; } c; c.w = v;
    __hip_atomic_store((unsigned long long*)p, c.u,
                       __ATOMIC_RELAXED, __HIP_MEMORY_SCOPE_AGENT);
}
#define FDOT2(w, x, c) __builtin_amdgcn_fdot2(as_h2(w), as_h2(x), (c), false)

// LDS layout (float slots) — shared by both persistent kernels
#define SM_WH     0            // uint[6][8][256] packed half2 weights = 12288
#define SM_BIAS   12288        // [2][8][128] biasA/biasB planes       = 2048
#define SM_DECH   14336        // uint[256] dec row packed             = 256
#define SM_BL     14592        // [2][8] L1/L2 scalar biases           = 16
#define SM_G      14608        // gate partials (8192 floats)
#define SM_DB     22800        // dec partials  (1024 floats)
#define SM_H      23824        // [2][128] h staging                   = 256
#define SM_TOTAL  24080        // floats -> 96320 bytes

// path-A workspace offsets (float units)
#define HSLOT   32768                  // uints per state slot (256 kp x 128 b)
#define NSLOT   65                     // t = -1 .. 63
#define HTOT    (3 * NSLOT * HSLOT)    // 6,389,760
#define OFF_C   HTOT
#define OFF_M   (OFF_C + 3*HB)
#define OFF_W0  (OFF_M + 4*HB)
#define OFF_BA  (OFF_W0 + 16*HB)
#define OFF_BB  (OFF_BA + 4*HB)
#define OFF_DV  (OFF_BB + 4*HB)
#define OFF_BAR (OFF_DV + 5120)
#define NEED_A  ((size_t)(OFF_BAR + 4160) * sizeof(float))

struct RnnParams {
  const float* w_hh0;
  const float* w_ihr;
  const float* w_hhr;
  const float* b_ihr;
  const float* b_hhr;
  const float* dec_w;
  const float* dec_b;
  const float* W0eff;
  const float* biasA;
  const float* biasB;
  unsigned int* h;      // path A: 3*65 slots; path B: 6 ping-pong buffers
  float* c;
  float* out;
  unsigned int* arrive;
  unsigned int* gocnt;
};

// ---- precompute kernels (round 1, verified; layout-agnostic) ---------------

__global__ __launch_bounds__(256) void k_init_a(
    const float* __restrict__ enc_w, const float* __restrict__ enc_b,
    const float* __restrict__ dec_b,
    unsigned int* __restrict__ h, float* __restrict__ c,
    float* __restrict__ d, float* __restrict__ nxt0,
    unsigned int* __restrict__ barptr)
{
    int idx = blockIdx.x * 256 + threadIdx.x;   // 65536 threads
    if (idx < 4160) barptr[idx] = 0u;
    if (idx < HSLOT) {
        #pragma unroll
        for (int l = 0; l < 3; ++l) h[(size_t)l * NSLOT * HSLOT + idx] = 0u;
    }
    #pragma unroll
    for (int i = 0; i < 3; ++i) c[i*HB + idx] = 0.f;
    if (idx < H) {
        float s = 0.f;
        for (int o = 0; o < O; ++o) s += enc_w[idx*O + o] * dec_b[o];
        d[idx] = enc_b[idx] + s;
        nxt0[idx] = enc_w[idx*O + 1] + enc_b[idx];
    }
}

__global__ __launch_bounds__(256) void k_init_b(
    const float* __restrict__ enc_w, const float* __restrict__ enc_b,
    const float* __restrict__ dec_b,
    float* __restrict__ h, float* __restrict__ c,
    float* __restrict__ d, float* __restrict__ nxt0,
    unsigned int* __restrict__ barptr)
{
    int idx = blockIdx.x * 256 + threadIdx.x;
    if (idx < 4160) barptr[idx] = 0u;
    #pragma unroll
    for (int i = 0; i < 3; ++i) h[i*HB + idx] = 0.f;
    #pragma unroll
    for (int i = 0; i < 3; ++i) c[i*HB + idx] = 0.f;
    if (idx < H) {
        float s = 0.f;
        for (int o = 0; o < O; ++o) s += enc_w[idx*O + o] * dec_b[o];
        d[idx] = enc_b[idx] + s;
        nxt0[idx] = enc_w[idx*O + 1] + enc_b[idx];
    }
}

__global__ __launch_bounds__(256) void k_M(
    const float* __restrict__ enc_w, const float* __restrict__ dec_w,
    float* __restrict__ M)
{
    int idx = blockIdx.x * 256 + threadIdx.x;
    int hh = idx >> 9, k = idx & 511;
    float s = 0.f;
    for (int o = 0; o < O; ++o) s += enc_w[hh*O + o] * dec_w[o*H + k];
    M[hh*H + k] = s;
}

__global__ __launch_bounds__(256) void k_cd(
    const float* __restrict__ w_ih0,
    const float* __restrict__ nxt0, const float* __restrict__ d,
    float* __restrict__ x0c, float* __restrict__ cd)
{
    int j = blockIdx.x * 256 + threadIdx.x;
    const float* row = w_ih0 + (size_t)j * (H + PP);
    float sA = 0.f, sB = 0.f;
    for (int k = 0; k < H; ++k) { float w = row[k]; sA += w * nxt0[k]; sB += w * d[k]; }
    x0c[j] = sA; cd[j] = sB;
}

__global__ __launch_bounds__(256) void k_W0eff(
    const float* __restrict__ w_ih0, const float* __restrict__ M,
    float* __restrict__ W0eff)
{
    int k0 = (threadIdx.x & 127) * 4;
    int jsub = threadIdx.x >> 7;
    int j0 = blockIdx.x * 16 + jsub * 8;
    float4 a[8];
    #pragma unroll
    for (int i = 0; i < 8; ++i) a[i] = make_float4(0.f, 0.f, 0.f, 0.f);
    for (int hh = 0; hh < H; ++hh) {
        float4 mv = *(const float4*)(M + (size_t)hh * H + k0);
        #pragma unroll
        for (int i = 0; i < 8; ++i) {
            float w = w_ih0[(size_t)(j0 + i) * (H + PP) + hh];
            a[i].x += w * mv.x; a[i].y += w * mv.y;
            a[i].z += w * mv.z; a[i].w += w * mv.w;
        }
    }
    #pragma unroll
    for (int i = 0; i < 8; ++i)
        *(float4*)(W0eff + (size_t)(j0 + i) * H + k0) = a[i];
}

__global__ __launch_bounds__(256) void k_bias(
    const float* __restrict__ w_ih0, const float* __restrict__ props,
    const float* __restrict__ b_ih0, const float* __restrict__ b_hh0,
    const float* __restrict__ x0c, const float* __restrict__ cd,
    float* __restrict__ biasA, float* __restrict__ biasB)
{
    int idx = blockIdx.x * 256 + threadIdx.x;
    int j = idx >> 7, b = idx & 127;
    const float* wp = w_ih0 + (size_t)j * (H + PP) + H;
    const float* pr = props + b * PP;
    float pc = wp[0]*pr[0] + wp[1]*pr[1] + wp[2]*pr[2] + wp[3]*pr[3];
    float base = b_ih0[j] + b_hh0[j] + pc;
    biasA[idx] = base + x0c[j];
    biasB[idx] = base + cd[j];
}

// ---- shared device helpers for the persistent kernels ----------------------

__device__ __forceinline__ void stage_weights(
    unsigned int* sWH, float* sBias, unsigned int* sDecH, float* sBL,
    const RnnParams& p, int wg, int u0, int tid, bool isdec)
{
    const float* bases[6] = { p.W0eff, p.w_hh0, p.w_ihr, p.w_hhr,
                              p.w_ihr + GH, p.w_hhr + GH };
    #pragma unroll
    for (int s = 0; s < 6; ++s) {
        for (int idx = tid; idx < 2048; idx += 512) {
            int r = idx >> 8, kp = idx & 255;
            int j = (r >> 1) * H + u0 + (r & 1);
            const float* src = bases[s] + (size_t)j * H + 2*kp;
            sWH[s*2048 + (r << 8) + kp] = pack2h(src[0], src[1]);
        }
    }
    for (int idx = tid; idx < 2048; idx += 512) {
        int pl = idx >> 10, r = (idx >> 7) & 7, b = idx & 127;
        int j = (r >> 1) * H + u0 + (r & 1);
        sBias[idx] = (pl ? p.biasB : p.biasA)[(size_t)j * B + b];
    }
    if (tid < 16) {
        int l = tid >> 3, r = tid & 7;
        int j = (r >> 1) * H + u0 + (r & 1);
        sBL[tid] = p.b_ihr[l*G + j] + p.b_hhr[l*G + j];
    }
    if (isdec && tid < 256) {
        const float* src = p.dec_w + (size_t)wg * H + 2*tid;
        sDecH[tid] = pack2h(src[0], src[1]);
    }
}

// ===========================================================================
// PATH A kernel: LDS-carried h-part hoist + split barrier w/ early aggregation
// ===========================================================================

__global__ __launch_bounds__(512, 2) void rnn_persistent_a(RnnParams p)
{
    extern __shared__ float sm[];
    const int tid   = threadIdx.x;
    const int wg    = blockIdx.x;       // owns units 2wg,2wg+1 == k-pair wg
    const int u0    = wg * 2;
    const int b4    = tid & 31;         // batches 4b4..4b4+3
    const int khalf = (tid >> 5) & 1;   // folded by shfl_xor(32)
    const int ks    = tid >> 6;         // wave [0,8)

    unsigned int* sWH   = (unsigned int*)(sm + SM_WH);
    float*        sBias = sm + SM_BIAS;
    unsigned int* sDecH = (unsigned int*)(sm + SM_DECH);
    float*        sBL   = sm + SM_BL;
    float*        sG    = sm + SM_G;    // [8r][8ks][32b4] x4
    float*        sDb   = sm + SM_DB;   // [8ks][32b4] x4
    float*        sH    = sm + SM_H;

    float* c0 = p.c; float* c1 = p.c + HB; float* c2 = p.c + 2*HB;
    const bool  isdec = (wg < O);
    const float decb  = isdec ? p.dec_b[wg] : 0.f;

    // one-time invalidate of pre-launch (poison-era) clean lines
    __builtin_amdgcn_fence(__ATOMIC_ACQUIRE, "agent");

    stage_weights(sWH, sBias, sDecH, sBL, p, wg, u0, tid, isdec);
    __syncthreads();

    unsigned int done = 0;              // barriers arrived at
    unsigned int* arrive = p.arrive;
    unsigned int* gocnt  = p.gocnt;

    // bar_arrive: sync (orders epilogue LDS reads vs next h_part writes, and
    // the release RMW drains the h agent-stores), arrive RMW; WG0 aggregates
    // the 256 flags IMMEDIATELY and posts go — overlapping others' h_part.
    auto bar_arrive = [&]() {
        __syncthreads();
        if (tid == 0)
            __hip_atomic_fetch_add(&arrive[(size_t)wg * 16], 1u,
                                   __ATOMIC_RELEASE, __HIP_MEMORY_SCOPE_AGENT);
        ++done;
        if (wg == 0) {
            if (tid < 256) {
                while (__hip_atomic_load(&arrive[(size_t)tid * 16],
                        __ATOMIC_RELAXED, __HIP_MEMORY_SCOPE_AGENT) < done)
                    __builtin_amdgcn_s_sleep(1);
            }
            __syncthreads();
            if (tid == 0)
                __hip_atomic_fetch_add(gocnt, 1u,
                                       __ATOMIC_RELEASE, __HIP_MEMORY_SCOPE_AGENT);
        }
    };
    // bar_wait: tid0 polls go, syncthreads broadcast (r10 population).
    auto bar_wait = [&]() {
        if (tid == 0) {
            while (__hip_atomic_load(gocnt, __ATOMIC_RELAXED,
                                     __HIP_MEMORY_SCOPE_AGENT) < done)
                __builtin_amdgcn_s_sleep(1);
        }
        __syncthreads();
    };

    auto slot = [&](int l, int s) -> unsigned int* {
        return p.h + ((size_t)(l * NSLOT + s) << 15);
    };

    const int kp0 = ks * 32 + khalf * 16;
    const int xo  = 4 * b4;

    // h-part: operand is 3 barriers old => runs BEFORE bar_wait. Partials go
    // to sG (registers die before the spin — the r11 spill fix).
    auto h_part = [&](const unsigned int* __restrict__ hs, int ph) {
        float4 acc[8];
        #pragma unroll
        for (int r = 0; r < 8; ++r) acc[r] = make_float4(0.f, 0.f, 0.f, 0.f);
        const unsigned int* wh = sWH + (ph*2 + 1) * 2048;
        for (int kp = kp0; kp < kp0 + 16; kp += 4) {
            uint4 x0 = *(const uint4*)(hs + (kp+0)*128 + xo);
            uint4 x1 = *(const uint4*)(hs + (kp+1)*128 + xo);
            uint4 x2 = *(const uint4*)(hs + (kp+2)*128 + xo);
            uint4 x3 = *(const uint4*)(hs + (kp+3)*128 + xo);
            #pragma unroll
            for (int r = 0; r < 8; ++r) {
                uint4 wq = *(const uint4*)(wh + r*256 + kp);
                acc[r].x = FDOT2(wq.x, x0.x, acc[r].x); acc[r].y = FDOT2(wq.x, x0.y, acc[r].y);
                acc[r].z = FDOT2(wq.x, x0.z, acc[r].z); acc[r].w = FDOT2(wq.x, x0.w, acc[r].w);
                acc[r].x = FDOT2(wq.y, x1.x, acc[r].x); acc[r].y = FDOT2(wq.y, x1.y, acc[r].y);
                acc[r].z = FDOT2(wq.y, x1.z, acc[r].z); acc[r].w = FDOT2(wq.y, x1.w, acc[r].w);
                acc[r].x = FDOT2(wq.z, x2.x, acc[r].x); acc[r].y = FDOT2(wq.z, x2.y, acc[r].y);
                acc[r].z = FDOT2(wq.z, x2.z, acc[r].z); acc[r].w = FDOT2(wq.z, x2.w, acc[r].w);
                acc[r].x = FDOT2(wq.w, x3.x, acc[r].x); acc[r].y = FDOT2(wq.w, x3.y, acc[r].y);
                acc[r].z = FDOT2(wq.w, x3.z, acc[r].z); acc[r].w = FDOT2(wq.w, x3.w, acc[r].w);
            }
        }
        #pragma unroll
        for (int r = 0; r < 8; ++r) {
            acc[r].x += __shfl_xor(acc[r].x, 32, 64);
            acc[r].y += __shfl_xor(acc[r].y, 32, 64);
            acc[r].z += __shfl_xor(acc[r].z, 32, 64);
            acc[r].w += __shfl_xor(acc[r].w, 32, 64);
        }
        if (khalf == 0) {
            #pragma unroll
            for (int r = 0; r < 8; ++r)
                *(float4*)(sG + ((r*8 + ks)*32 + b4)*4) = acc[r];   // partials
        }
    };

    // x-part + same-thread sG accumulate + epilogue + store (after bar_wait)
    auto x_part_finish = [&](const unsigned int* __restrict__ xs, int ph,
                             const float* biasPlane, const float* biasScal,
                             float* cc, unsigned int* hout,
                             bool dopig, float* dout) {
        float4 acc[8];
        #pragma unroll
        for (int r = 0; r < 8; ++r) acc[r] = make_float4(0.f, 0.f, 0.f, 0.f);
        float4 accd = make_float4(0.f, 0.f, 0.f, 0.f);
        const unsigned int* wx = sWH + (ph*2 + 0) * 2048;
        for (int kp = kp0; kp < kp0 + 16; kp += 4) {
            uint4 x0 = *(const uint4*)(xs + (kp+0)*128 + xo);
            uint4 x1 = *(const uint4*)(xs + (kp+1)*128 + xo);
            uint4 x2 = *(const uint4*)(xs + (kp+2)*128 + xo);
            uint4 x3 = *(const uint4*)(xs + (kp+3)*128 + xo);
            #pragma unroll
            for (int r = 0; r < 8; ++r) {
                uint4 wq = *(const uint4*)(wx + r*256 + kp);
                acc[r].x = FDOT2(wq.x, x0.x, acc[r].x); acc[r].y = FDOT2(wq.x, x0.y, acc[r].y);
                acc[r].z = FDOT2(wq.x, x0.z, acc[r].z); acc[r].w = FDOT2(wq.x, x0.w, acc[r].w);
                acc[r].x = FDOT2(wq.y, x1.x, acc[r].x); acc[r].y = FDOT2(wq.y, x1.y, acc[r].y);
                acc[r].z = FDOT2(wq.y, x1.z, acc[r].z); acc[r].w = FDOT2(wq.y, x1.w, acc[r].w);
                acc[r].x = FDOT2(wq.z, x2.x, acc[r].x); acc[r].y = FDOT2(wq.z, x2.y, acc[r].y);
                acc[r].z = FDOT2(wq.z, x2.z, acc[r].z); acc[r].w = FDOT2(wq.z, x2.w, acc[r].w);
                acc[r].x = FDOT2(wq.w, x3.x, acc[r].x); acc[r].y = FDOT2(wq.w, x3.y, acc[r].y);
                acc[r].z = FDOT2(wq.w, x3.z, acc[r].z); acc[r].w = FDOT2(wq.w, x3.w, acc[r].w);
            }
            if (dopig) {
                uint4 dq = *(const uint4*)(sDecH + kp);
                accd.x = FDOT2(dq.x, x0.x, accd.x); accd.y = FDOT2(dq.x, x0.y, accd.y);
                accd.z = FDOT2(dq.x, x0.z, accd.z); accd.w = FDOT2(dq.x, x0.w, accd.w);
                accd.x = FDOT2(dq.y, x1.x, accd.x); accd.y = FDOT2(dq.y, x1.y, accd.y);
                accd.z = FDOT2(dq.y, x1.z, accd.z); accd.w = FDOT2(dq.y, x1.w, accd.w);
                accd.x = FDOT2(dq.z, x2.x, accd.x); accd.y = FDOT2(dq.z, x2.y, accd.y);
                accd.z = FDOT2(dq.z, x2.z, accd.z); accd.w = FDOT2(dq.z, x2.w, accd.w);
                accd.x = FDOT2(dq.w, x3.x, accd.x); accd.y = FDOT2(dq.w, x3.y, accd.y);
                accd.z = FDOT2(dq.w, x3.z, accd.z); accd.w = FDOT2(dq.w, x3.w, accd.w);
            }
        }

        #pragma unroll
        for (int r = 0; r < 8; ++r) {
            acc[r].x += __shfl_xor(acc[r].x, 32, 64);
            acc[r].y += __shfl_xor(acc[r].y, 32, 64);
            acc[r].z += __shfl_xor(acc[r].z, 32, 64);
            acc[r].w += __shfl_xor(acc[r].w, 32, 64);
        }
        if (khalf == 0) {          // same-thread RMW: add h-part partials
            #pragma unroll
            for (int r = 0; r < 8; ++r) {
                float4* gp = (float4*)(sG + ((r*8 + ks)*32 + b4)*4);
                float4 hv = *gp;
                hv.x += acc[r].x; hv.y += acc[r].y;
                hv.z += acc[r].z; hv.w += acc[r].w;
                *gp = hv;
            }
        }
        if (dopig) {
            accd.x += __shfl_xor(accd.x, 32, 64);
            accd.y += __shfl_xor(accd.y, 32, 64);
            accd.z += __shfl_xor(accd.z, 32, 64);
            accd.w += __shfl_xor(accd.w, 32, 64);
            if (khalf == 0) *(float4*)(sDb + (ks*32 + b4)*4) = accd;
        }
        __syncthreads();

        if (tid < 256) {
            int mi = tid >> 7, b = tid & 127;
            float g[4];
            #pragma unroll
            for (int q = 0; q < 4; ++q) {
                int r = q*2 + mi;
                float s = biasPlane ? biasPlane[r*128 + b] : biasScal[r];
                #pragma unroll
                for (int k2 = 0; k2 < 8; ++k2)
                    s += sG[((r*8 + k2)*32 + (b >> 2))*4 + (b & 3)];
                g[q] = s;
            }
            float ig = 1.f/(1.f+expf(-g[0]));
            float fg = 1.f/(1.f+expf(-g[1]));
            float gv = tanhf(g[2]);
            float og = 1.f/(1.f+expf(-g[3]));
            int idx = (u0 + mi)*B + b;
            float cn = fg*cc[idx] + ig*gv;
            cc[idx] = cn;
            sH[mi*128 + b] = og*tanhf(cn);
        } else if (dopig && tid < 384) {
            int b = tid - 256;
            float s = decb;
            #pragma unroll
            for (int k2 = 0; k2 < 8; ++k2)
                s += sDb[(k2*32 + (b >> 2))*4 + (b & 3)];
            dout[(size_t)b * (T*O)] = s;
        }
        __syncthreads();
        if (tid < 64) {                       // pack k-pair x 2 batches -> 8B
            int b0 = tid * 2;
            uint2 v;
            v.x = pack2h(sH[b0],     sH[128 + b0]);
            v.y = pack2h(sH[b0 + 1], sH[128 + b0 + 1]);
            cstore_u2(hout + wg*128 + b0, v);   // agent store -> IF
        }
    };

    for (int t = 0; t < T; ++t) {
        bool pig = (t > 0) && isdec;
        // phase L0
        h_part(slot(0, t), 0);
        bar_wait();
        x_part_finish(slot(2, t), 0, sBias + (t == 0 ? 0 : 1024), nullptr,
                      c0, slot(0, t+1), pig,
                      pig ? (p.out + (size_t)(t-1)*O + wg) : nullptr);
        bar_arrive();
        // phase L1
        h_part(slot(1, t), 1);
        bar_wait();
        x_part_finish(slot(0, t+1), 1, nullptr, sBL, c1, slot(1, t+1),
                      false, nullptr);
        bar_arrive();
        // phase L2
        h_part(slot(2, t), 2);
        bar_wait();
        x_part_finish(slot(1, t+1), 2, nullptr, sBL + 8, c2, slot(2, t+1),
                      false, nullptr);
        bar_arrive();
    }

    // final logits from slot(2, 64) — wait for the last barrier first
    bar_wait();
    if (isdec) {
        const unsigned int* xs = slot(2, T);
        float4 accd = make_float4(0.f, 0.f, 0.f, 0.f);
        for (int kp = kp0; kp < kp0 + 16; kp += 4) {
            uint4 x0 = *(const uint4*)(xs + (kp+0)*128 + xo);
            uint4 x1 = *(const uint4*)(xs + (kp+1)*128 + xo);
            uint4 x2 = *(const uint4*)(xs + (kp+2)*128 + xo);
            uint4 x3 = *(const uint4*)(xs + (kp+3)*128 + xo);
            uint4 dq = *(const uint4*)(sDecH + kp);
            accd.x = FDOT2(dq.x, x0.x, accd.x); accd.y = FDOT2(dq.x, x0.y, accd.y);
            accd.z = FDOT2(dq.x, x0.z, accd.z); accd.w = FDOT2(dq.x, x0.w, accd.w);
            accd.x = FDOT2(dq.y, x1.x, accd.x); accd.y = FDOT2(dq.y, x1.y, accd.y);
            accd.z = FDOT2(dq.y, x1.z, accd.z); accd.w = FDOT2(dq.y, x1.w, accd.w);
            accd.x = FDOT2(dq.z, x2.x, accd.x); accd.y = FDOT2(dq.z, x2.y, accd.y);
            accd.z = FDOT2(dq.z, x2.z, accd.z); accd.w = FDOT2(dq.z, x2.w, accd.w);
            accd.x = FDOT2(dq.w, x3.x, accd.x); accd.y = FDOT2(dq.w, x3.y, accd.y);
            accd.z = FDOT2(dq.w, x3.z, accd.z); accd.w = FDOT2(dq.w, x3.w, accd.w);
        }
        accd.x += __shfl_xor(accd.x, 32, 64);
        accd.y += __shfl_xor(accd.y, 32, 64);
        accd.z += __shfl_xor(accd.z, 32, 64);
        accd.w += __shfl_xor(accd.w, 32, 64);
        if (khalf == 0) *(float4*)(sDb + (ks*32 + b4)*4) = accd;
    }
    __syncthreads();
    if (isdec && tid < 128) {
        int b = tid;
        float s = decb;
        #pragma unroll
        for (int k2 = 0; k2 < 8; ++k2)
            s += sDb[(k2*32 + (b >> 2))*4 + (b & 3)];
        p.out[((size_t)b * T + 63) * O + wg] = s;
    }
}

// ===========================================================================
// PATH B kernel: round-9 (proven 2.45 ms) — agent 8B loads, ping-pong state
// ===========================================================================

__global__ __launch_bounds__(512, 2) void rnn_persistent_b(RnnParams p)
{
    extern __shared__ float sm[];
    const int tid = threadIdx.x;
    const int wg  = blockIdx.x;
    const int u0  = wg * 2;
    const int b2  = tid & 63;
    const int ks  = tid >> 6;

    unsigned int* sWH   = (unsigned int*)(sm + SM_WH);
    float*        sBias = sm + SM_BIAS;
    unsigned int* sDecH = (unsigned int*)(sm + SM_DECH);
    float*        sBL   = sm + SM_BL;
    float2*       sGbuf = (float2*)(sm + SM_G);
    float2*       sDecb = (float2*)(sm + SM_DB);
    float*        sH    = sm + SM_H;

    unsigned int* h0p = p.h + 0*32768; unsigned int* h0c = p.h + 1*32768;
    unsigned int* h1p = p.h + 2*32768; unsigned int* h1c = p.h + 3*32768;
    unsigned int* h2p = p.h + 4*32768; unsigned int* h2c = p.h + 5*32768;
    float* c0 = p.c; float* c1 = p.c + HB; float* c2 = p.c + 2*HB;

    const bool  isdec = (wg < O);
    const float decb  = isdec ? p.dec_b[wg] : 0.f;

    stage_weights(sWH, sBias, sDecH, sBL, p, wg, u0, tid, isdec);
    __syncthreads();

    unsigned int epoch = 0;
    unsigned int* arrive = p.arrive;
    unsigned int* gocnt  = p.gocnt;
    auto gbar = [&]() {
        ++epoch;
        __syncthreads();
        if (tid == 0)
            __hip_atomic_fetch_add(&arrive[(size_t)wg * 16], 1u,
                                   __ATOMIC_RELEASE, __HIP_MEMORY_SCOPE_AGENT);
        if (wg == 0) {
            if (tid < 256) {
                while (__hip_atomic_load(&arrive[(size_t)tid * 16],
                        __ATOMIC_RELAXED, __HIP_MEMORY_SCOPE_AGENT) < epoch)
                    __builtin_amdgcn_s_sleep(1);
            }
            __syncthreads();
            if (tid == 0)
                __hip_atomic_fetch_add(gocnt, 1u,
                                       __ATOMIC_RELEASE, __HIP_MEMORY_SCOPE_AGENT);
        }
        if (tid == 0) {
            while (__hip_atomic_load(gocnt, __ATOMIC_RELAXED,
                                     __HIP_MEMORY_SCOPE_AGENT) < epoch)
                __builtin_amdgcn_s_sleep(1);
        }
        __syncthreads();
    };

    auto phase = [&](const unsigned int* __restrict__ xs,
                     const unsigned int* __restrict__ hs,
                     int ph, const float* biasPlane, const float* biasScal,
                     float* cc, unsigned int* hout, bool dopig, float* dout) {
        float2 acc[8];
        #pragma unroll
        for (int r = 0; r < 8; ++r) { acc[r].x = 0.f; acc[r].y = 0.f; }
        float2 accd; accd.x = 0.f; accd.y = 0.f;

        const unsigned int* wx = sWH + (ph*2 + 0) * 2048;
        const unsigned int* wh = sWH + (ph*2 + 1) * 2048;
        const int kb = ks * 32;
        const int xo = 2 * b2;

        for (int kp = kb; kp < kb + 32; kp += 4) {
            uint2 x0 = cload_u2(xs + (kp+0)*128 + xo);
            uint2 x1 = cload_u2(xs + (kp+1)*128 + xo);
            uint2 x2 = cload_u2(xs + (kp+2)*128 + xo);
            uint2 x3 = cload_u2(xs + (kp+3)*128 + xo);
            if (dopig) {
                uint4 dq = *(const uint4*)(sDecH + kp);
                accd.x = FDOT2(dq.x, x0.x, accd.x); accd.y = FDOT2(dq.x, x0.y, accd.y);
                accd.x = FDOT2(dq.y, x1.x, accd.x); accd.y = FDOT2(dq.y, x1.y, accd.y);
                accd.x = FDOT2(dq.z, x2.x, accd.x); accd.y = FDOT2(dq.z, x2.y, accd.y);
                accd.x = FDOT2(dq.w, x3.x, accd.x); accd.y = FDOT2(dq.w, x3.y, accd.y);
            }
            #pragma unroll
            for (int r = 0; r < 8; ++r) {
                uint4 wq = *(const uint4*)(wx + r*256 + kp);
                acc[r].x = FDOT2(wq.x, x0.x, acc[r].x); acc[r].y = FDOT2(wq.x, x0.y, acc[r].y);
                acc[r].x = FDOT2(wq.y, x1.x, acc[r].x); acc[r].y = FDOT2(wq.y, x1.y, acc[r].y);
                acc[r].x = FDOT2(wq.z, x2.x, acc[r].x); acc[r].y = FDOT2(wq.z, x2.y, acc[r].y);
                acc[r].x = FDOT2(wq.w, x3.x, acc[r].x); acc[r].y = FDOT2(wq.w, x3.y, acc[r].y);
            }
        }
        for (int kp = kb; kp < kb + 32; kp += 4) {
            uint2 x0 = cload_u2(hs + (kp+0)*128 + xo);
            uint2 x1 = cload_u2(hs + (kp+1)*128 + xo);
            uint2 x2 = cload_u2(hs + (kp+2)*128 + xo);
            uint2 x3 = cload_u2(hs + (kp+3)*128 + xo);
            #pragma unroll
            for (int r = 0; r < 8; ++r) {
                uint4 wq = *(const uint4*)(wh + r*256 + kp);
                acc[r].x = FDOT2(wq.x, x0.x, acc[r].x); acc[r].y = FDOT2(wq.x, x0.y, acc[r].y);
                acc[r].x = FDOT2(wq.y, x1.x, acc[r].x); acc[r].y = FDOT2(wq.y, x1.y, acc[r].y);
                acc[r].x = FDOT2(wq.z, x2.x, acc[r].x); acc[r].y = FDOT2(wq.z, x2.y, acc[r].y);
                acc[r].x = FDOT2(wq.w, x3.x, acc[r].x); acc[r].y = FDOT2(wq.w, x3.y, acc[r].y);
            }
        }

        #pragma unroll
        for (int r = 0; r < 8; ++r) sGbuf[(r*8 + ks)*64 + b2] = acc[r];
        if (dopig) sDecb[ks*64 + b2] = accd;
        __syncthreads();

        if (tid < 256) {
            int mi = tid >> 7, b = tid & 127;
            float g[4];
            #pragma unroll
            for (int q = 0; q < 4; ++q) {
                int r = q*2 + mi;
                float s = biasPlane ? biasPlane[r*128 + b] : biasScal[r];
                #pragma unroll
                for (int k2 = 0; k2 < 8; ++k2) {
                    float2 v = sGbuf[(r*8 + k2)*64 + (b >> 1)];
                    s += (b & 1) ? v.y : v.x;
                }
                g[q] = s;
            }
            float ig = 1.f/(1.f+expf(-g[0]));
            float fg = 1.f/(1.f+expf(-g[1]));
            float gv = tanhf(g[2]);
            float og = 1.f/(1.f+expf(-g[3]));
            int idx = (u0 + mi)*B + b;
            float cn = fg*cc[idx] + ig*gv;
            cc[idx] = cn;
            sH[mi*128 + b] = og*tanhf(cn);
        } else if (dopig && tid < 384) {
            int b = tid - 256;
            float s = decb;
            #pragma unroll
            for (int k2 = 0; k2 < 8; ++k2) {
                float2 v = sDecb[k2*64 + (b >> 1)];
                s += (b & 1) ? v.y : v.x;
            }
            dout[(size_t)b * (T*O)] = s;
        }
        __syncthreads();
        if (tid < 64) {
            int b0 = tid * 2;
            uint2 v;
            v.x = pack2h(sH[b0],     sH[128 + b0]);
            v.y = pack2h(sH[b0 + 1], sH[128 + b0 + 1]);
            cstore_u2(hout + wg*128 + b0, v);
        }
    };

    for (int t = 0; t < T; ++t) {
        bool pig = (t > 0) && isdec;
        phase(h2p, h0p, 0, sBias + (t == 0 ? 0 : 1024), nullptr,
              c0, h0c, pig, pig ? (p.out + (size_t)(t-1)*O + wg) : nullptr);
        gbar();
        phase(h0c, h1p, 1, nullptr, sBL, c1, h1c, false, nullptr);
        gbar();
        phase(h1c, h2p, 2, nullptr, sBL + 8, c2, h2c, false, nullptr);
        gbar();
        unsigned int* tp;
        tp = h0p; h0p = h0c; h0c = tp;
        tp = h1p; h1p = h1c; h1c = tp;
        tp = h2p; h2p = h2c; h2c = tp;
    }

    if (isdec) {
        float2 accd; accd.x = 0.f; accd.y = 0.f;
        const int kb = ks * 32;
        const int xo = 2 * b2;
        for (int kp = kb; kp < kb + 32; kp += 4) {
            uint2 x0 = cload_u2(h2p + (kp+0)*128 + xo);
            uint2 x1 = cload_u2(h2p + (kp+1)*128 + xo);
            uint2 x2 = cload_u2(h2p + (kp+2)*128 + xo);
            uint2 x3 = cload_u2(h2p + (kp+3)*128 + xo);
            uint4 dq = *(const uint4*)(sDecH + kp);
            accd.x = FDOT2(dq.x, x0.x, accd.x); accd.y = FDOT2(dq.x, x0.y, accd.y);
            accd.x = FDOT2(dq.y, x1.x, accd.x); accd.y = FDOT2(dq.y, x1.y, accd.y);
            accd.x = FDOT2(dq.z, x2.x, accd.x); accd.y = FDOT2(dq.z, x2.y, accd.y);
            accd.x = FDOT2(dq.w, x3.x, accd.x); accd.y = FDOT2(dq.w, x3.y, accd.y);
        }
        sDecb[ks*64 + b2] = accd;
    }
    __syncthreads();
    if (isdec && tid < 128) {
        int b = tid;
        float s = decb;
        #pragma unroll
        for (int k2 = 0; k2 < 8; ++k2) {
            float2 v = sDecb[k2*64 + (b >> 1)];
            s += (b & 1) ? v.y : v.x;
        }
        p.out[((size_t)b * T + 63) * O + wg] = s;
    }
}

// ===========================================================================
// LEGACY FALLBACK (round-0, proven correct)
// ===========================================================================

__global__ __launch_bounds__(256) void init_kernel(
    const float* __restrict__ enc_w, const float* __restrict__ enc_b,
    float* __restrict__ nxtT, float* __restrict__ hbufs, float* __restrict__ cbufs)
{
    int idx = blockIdx.x * 256 + threadIdx.x;
    #pragma unroll
    for (int i = 0; i < 6; ++i) hbufs[i * HB + idx] = 0.f;
    #pragma unroll
    for (int i = 0; i < 3; ++i) cbufs[i * HB + idx] = 0.f;
    int h = idx >> 7;
    nxtT[idx] = enc_w[h * O + 1] + enc_b[h];
}

__global__ __launch_bounds__(256) void transpose_kernel(
    const float* __restrict__ dec_w, const float* __restrict__ enc_w,
    float* __restrict__ dec_wT, float* __restrict__ enc_wT)
{
    int idx = blockIdx.x * 256 + threadIdx.x;
    if (idx < O * H) {
        int o = idx / H, k = idx - o * H;
        dec_wT[k * O + o] = dec_w[o * H + k];
        enc_wT[o * H + k] = enc_w[k * O + o];
    }
}

__global__ __launch_bounds__(512) void gates_kernel(
    const float* __restrict__ xT, const float* __restrict__ hT,
    const float* __restrict__ w_ih, int ldih,
    const float* __restrict__ w_hh,
    const float* __restrict__ b_ih, const float* __restrict__ b_hh,
    const float* __restrict__ props,
    float* __restrict__ c, float* __restrict__ hout)
{
    const int wg = blockIdx.x;
    const int bg = wg >> 7, jg = wg & 127;
    const int m0 = jg * 4;
    const int lane_b = threadIdx.x & 63, ks = threadIdx.x >> 6;
    const int bb = (bg << 6) + lane_b;
    float acc[16];
    #pragma unroll
    for (int r = 0; r < 16; ++r) acc[r] = 0.f;
    const float* wih_rows[16]; const float* whh_rows[16];
    #pragma unroll
    for (int q = 0; q < 4; ++q)
        #pragma unroll
        for (int mi = 0; mi < 4; ++mi) {
            int r = q * 4 + mi, j = q * H + m0 + mi;
            wih_rows[r] = w_ih + (size_t)j * ldih;
            whh_rows[r] = w_hh + (size_t)j * H;
        }
    const int kbeg = ks * 64, kend = ks * 64 + 64;
    for (int k0 = kbeg; k0 < kend; k0 += 4) {
        float x0 = xT[(k0+0)*B+bb], x1 = xT[(k0+1)*B+bb];
        float x2 = xT[(k0+2)*B+bb], x3 = xT[(k0+3)*B+bb];
        #pragma unroll
        for (int r = 0; r < 16; ++r) {
            float4 wv = *(const float4*)(wih_rows[r] + k0);
            acc[r] += wv.x*x0 + wv.y*x1 + wv.z*x2 + wv.w*x3;
        }
    }
    for (int k0 = kbeg; k0 < kend; k0 += 4) {
        float x0 = hT[(k0+0)*B+bb], x1 = hT[(k0+1)*B+bb];
        float x2 = hT[(k0+2)*B+bb], x3 = hT[(k0+3)*B+bb];
        #pragma unroll
        for (int r = 0; r < 16; ++r) {
            float4 wv = *(const float4*)(whh_rows[r] + k0);
            acc[r] += wv.x*x0 + wv.y*x1 + wv.z*x2 + wv.w*x3;
        }
    }
    __shared__ float gbuf[16][8][64];
    #pragma unroll
    for (int r = 0; r < 16; ++r) gbuf[r][ks][lane_b] = acc[r];
    __syncthreads();
    if (threadIdx.x < 256) {
        int mi = threadIdx.x >> 6, b = threadIdx.x & 63;
        int bbo = (bg << 6) + b, m = m0 + mi;
        float g[4];
        #pragma unroll
        for (int q = 0; q < 4; ++q) {
            int j = q * H + m;
            float s = b_ih[j] + b_hh[j];
            #pragma unroll
            for (int k2 = 0; k2 < 8; ++k2) s += gbuf[q*4+mi][k2][b];
            if (props) {
                const float* wp = w_ih + (size_t)j * ldih + H;
                const float* pp = props + bbo * PP;
                s += wp[0]*pp[0] + wp[1]*pp[1] + wp[2]*pp[2] + wp[3]*pp[3];
            }
            g[q] = s;
        }
        float ig = 1.f/(1.f+expf(-g[0]));
        float fg = 1.f/(1.f+expf(-g[1]));
        float gv = tanhf(g[2]);
        float og = 1.f/(1.f+expf(-g[3]));
        int idx = m * B + bbo;
        float cn = fg * c[idx] + ig * gv;
        c[idx] = cn;
        hout[idx] = og * tanhf(cn);
    }
}

__global__ __launch_bounds__(256) void decenc_kernel(
    const float* __restrict__ h2T, const float* __restrict__ dec_wT,
    const float* __restrict__ dec_b, const float* __restrict__ enc_wT,
    const float* __restrict__ enc_b, float* __restrict__ nxtT,
    float* __restrict__ out, int t)
{
    const int b = blockIdx.x;
    const int w = threadIdx.x >> 6, o = threadIdx.x & 63;
    __shared__ float red[4][64];
    __shared__ float lg[64];
    float p = 0.f;
    if (o < O)
        for (int k = w * 128; k < w * 128 + 128; ++k)
            p += h2T[k * B + b] * dec_wT[k * O + o];
    red[w][o] = p;
    __syncthreads();
    if (threadIdx.x < 64) {
        int oo = threadIdx.x;
        float s = 0.f;
        if (oo < O) {
            s = dec_b[oo] + red[0][oo] + red[1][oo] + red[2][oo] + red[3][oo];
            out[((size_t)b * T + t) * O + oo] = s;
        }
        lg[oo] = s;
    }
    __syncthreads();
    for (int h = threadIdx.x; h < H; h += 256) {
        float s = enc_b[h];
        #pragma unroll 1
        for (int oo = 0; oo < O; ++oo) s += lg[oo] * enc_wT[oo * H + h];
        nxtT[h * B + b] = s;
    }
}

// ===========================================================================
extern "C" void kernel_launch(void* const* d_in, const int* in_sizes, int n_in,
                              void* d_out, int out_size, void* d_ws, size_t ws_size,
                              hipStream_t stream) {
    const float* props = (const float*)d_in[1];
    const float* enc_w = (const float*)d_in[2];
    const float* enc_b = (const float*)d_in[3];
    const float* dec_w = (const float*)d_in[4];
    const float* dec_b = (const float*)d_in[5];
    const float* w_ih0 = (const float*)d_in[6];
    const float* w_hh0 = (const float*)d_in[7];
    const float* b_ih0 = (const float*)d_in[8];
    const float* b_hh0 = (const float*)d_in[9];
    const float* w_ihr = (const float*)d_in[10];
    const float* w_hhr = (const float*)d_in[11];
    const float* b_ihr = (const float*)d_in[12];
    const float* b_hhr = (const float*)d_in[13];

    float* ws = (float*)d_ws;
    const size_t NEED_B = ((size_t)34 * HB + 5120 + 4160) * sizeof(float);
    const size_t LDS_BYTES = (size_t)SM_TOTAL * sizeof(float);

    static int lds_a = -1, lds_b = -1;
    if (lds_a < 0) {
        lds_a = (hipFuncSetAttribute((const void*)rnn_persistent_a,
                  hipFuncAttributeMaxDynamicSharedMemorySize,
                  (int)LDS_BYTES) == hipSuccess) ? 1 : 0;
        lds_b = (hipFuncSetAttribute((const void*)rnn_persistent_b,
                  hipFuncAttributeMaxDynamicSharedMemorySize,
                  (int)LDS_BYTES) == hipSuccess) ? 1 : 0;
    }

    if (ws_size >= NEED_A && lds_a == 1) {
        // ---- PATH A ----
        unsigned int* hbuf = (unsigned int*)ws;
        float* cbuf  = ws + OFF_C;
        float* M     = ws + OFF_M;
        float* W0eff = ws + OFF_W0;
        float* biasA = ws + OFF_BA;
        float* biasB = ws + OFF_BB;
        float* dvec  = ws + OFF_DV;
        float* nxt0  = dvec + 512;
        float* x0c   = nxt0 + 512;
        float* cd    = x0c + 2048;
        unsigned int* barptr = (unsigned int*)(ws + OFF_BAR);

        k_init_a<<<256, 256, 0, stream>>>(enc_w, enc_b, dec_b, hbuf, cbuf,
                                          dvec, nxt0, barptr);
        k_M<<<1024, 256, 0, stream>>>(enc_w, dec_w, M);
        k_cd<<<8, 256, 0, stream>>>(w_ih0, nxt0, dvec, x0c, cd);
        k_W0eff<<<128, 256, 0, stream>>>(w_ih0, M, W0eff);
        k_bias<<<1024, 256, 0, stream>>>(w_ih0, props, b_ih0, b_hh0, x0c, cd,
                                         biasA, biasB);

        RnnParams prm;
        prm.w_hh0 = w_hh0; prm.w_ihr = w_ihr; prm.w_hhr = w_hhr;
        prm.b_ihr = b_ihr; prm.b_hhr = b_hhr;
        prm.dec_w = dec_w; prm.dec_b = dec_b;
        prm.W0eff = W0eff; prm.biasA = biasA; prm.biasB = biasB;
        prm.h = hbuf; prm.c = cbuf; prm.out = (float*)d_out;
        prm.arrive = barptr; prm.gocnt = barptr + 4096;

        void* args[] = { &prm };
        hipLaunchCooperativeKernel((const void*)rnn_persistent_a,
                                   dim3(256), dim3(512), args,
                                   (unsigned int)LDS_BYTES, stream);
        return;
    }

    if (ws_size >= NEED_B && lds_b == 1) {
        // ---- PATH B: round-9 proven kernel ----
        unsigned int* hbuf = (unsigned int*)ws;
        float* cbuf  = ws + 3*HB;
        float* M     = ws + 6*HB;
        float* W0eff = ws + 10*HB;
        float* biasA = ws + 26*HB;
        float* biasB = ws + 30*HB;
        float* dvec  = ws + 34*HB;
        float* nxt0  = dvec + 512;
        float* x0c   = nxt0 + 512;
        float* cd    = x0c + 2048;
        unsigned int* barptr = (unsigned int*)(cd + 2048);

        k_init_b<<<256, 256, 0, stream>>>(enc_w, enc_b, dec_b, (float*)hbuf,
                                          cbuf, dvec, nxt0, barptr);
        k_M<<<1024, 256, 0, stream>>>(enc_w, dec_w, M);
        k_cd<<<8, 256, 0, stream>>>(w_ih0, nxt0, dvec, x0c, cd);
        k_W0eff<<<128, 256, 0, stream>>>(w_ih0, M, W0eff);
        k_bias<<<1024, 256, 0, stream>>>(w_ih0, props, b_ih0, b_hh0, x0c, cd,
                                         biasA, biasB);

        RnnParams prm;
        prm.w_hh0 = w_hh0; prm.w_ihr = w_ihr; prm.w_hhr = w_hhr;
        prm.b_ihr = b_ihr; prm.b_hhr = b_hhr;
        prm.dec_w = dec_w; prm.dec_b = dec_b;
        prm.W0eff = W0eff; prm.biasA = biasA; prm.biasB = biasB;
        prm.h = hbuf; prm.c = cbuf; prm.out = (float*)d_out;
        prm.arrive = barptr; prm.gocnt = barptr + 4096;

        void* args[] = { &prm };
        hipLaunchCooperativeKernel((const void*)rnn_persistent_b,
                                   dim3(256), dim3(512), args,
                                   (unsigned int)LDS_BYTES, stream);
        return;
    }

    // ---- legacy multi-launch fallback ----
    float* nxtT   = ws;
    float* hb     = ws + HB;
    float* cb     = ws + 7*HB;
    float* dec_wT = ws + 10*HB;
    float* enc_wT = dec_wT + H*O;

    init_kernel<<<256, 256, 0, stream>>>(enc_w, enc_b, nxtT, hb, cb);
    transpose_kernel<<<(O*H + 255)/256, 256, 0, stream>>>(dec_w, enc_w, dec_wT, enc_wT);

    float* hprev[3]; float* hcur[3];
    for (int l = 0; l < 3; ++l) { hprev[l] = hb + (2*l)*HB; hcur[l] = hb + (2*l+1)*HB; }

    for (int t = 0; t < T; ++t) {
        gates_kernel<<<256, 512, 0, stream>>>(nxtT, hprev[0], w_ih0, H+PP, w_hh0,
                                              b_ih0, b_hh0, props, cb, hcur[0]);
        gates_kernel<<<256, 512, 0, stream>>>(hcur[0], hprev[1], w_ihr, H, w_hhr,
                                              b_ihr, b_hhr, nullptr, cb + HB, hcur[1]);
        gates_kernel<<<256, 512, 0, stream>>>(hcur[1], hprev[2], w_ihr + (size_t)G*H, H,
                                              w_hhr + (size_t)G*H, b_ihr + G, b_hhr + G,
                                              nullptr, cb + 2*HB, hcur[2]);
        decenc_kernel<<<B, 256, 0, stream>>>(hcur[2], dec_wT, dec_b, enc_wT, enc_b,
                                             nxtT, (float*)d_out, t);
        for (int l = 0; l < 3; ++l) { float* tp = hprev[l]; hprev[l] = hcur[l]; hcur[l] = tp; }
    }
}